// Round 8
// baseline (1772.733 us; speedup 1.0000x reference)
//
#include <hip/hip_runtime.h>
#include <math.h>

#define NNODES 50000
#define NEDGES 800000
#define HDIM 128
#define NINV 32
#define K1 288            // 2H + NINV
#define NTILES_E 25000    // NEDGES / 32
#define NTILES_N 1563     // ceil(NNODES / 32)
#define NB 196            // scan blocks: 196*256 = 50176 >= NNODES

#define PREP_NB 400       // 102400 weight elems / 256
#define X2BF_NB 3125      // 800000 groups of 8 / 256
#define HIST_NB 3125      // 800000 edges / 256

#define HSTRIDE 132       // h-buffer row stride in ushorts (128+4): 66 dw == 2 mod 32 -> u16 writes 2-way free
#define FSTRIDE 66        // same buffer viewed as f32: 66 dw/row (64 cols + 2 pad)

typedef float floatx4 __attribute__((ext_vector_type(4)));
typedef short short8  __attribute__((ext_vector_type(8)));

union V4S8 { uint4 u; short8 s; int2 d[2]; };

__device__ __forceinline__ float silu_f(float z) { return z / (1.0f + __expf(-z)); }

__device__ __forceinline__ unsigned short f2bf_rne(float f) {
    unsigned u = __float_as_uint(f);
    u += 0x7fffu + ((u >> 16) & 1u);
    return (unsigned short)(u >> 16);
}

// pack hi16(bf-truncate) of two floats into one dword: [lo | hi<<16]
__device__ __forceinline__ unsigned pk_bf(float hi, float lo) {
    return __builtin_amdgcn_perm(__float_as_uint(hi), __float_as_uint(lo), 0x07060302);
}

__device__ __forceinline__ short8 cvt8(float4 f0, float4 f1) {
    V4S8 v;
    v.u.x = pk_bf(f0.y, f0.x);
    v.u.y = pk_bf(f0.w, f0.z);
    v.u.z = pk_bf(f1.y, f1.x);
    v.u.w = pk_bf(f1.w, f1.z);
    return v.s;
}

__device__ __forceinline__ int adj_at(const void* adj, int is64, long long pos) {
    if (is64) return (int)((const long long*)adj)[pos];
    return ((const int*)adj)[pos];
}

// Per-wave inline int64-vs-int32 detection: odd dwords of the first 256
// qword-slots are all zero iff adj is int64 (indices < 2^31).
__device__ __forceinline__ int detect64(const int* __restrict__ adj32) {
    int l = threadIdx.x & 63;
    int v = adj32[2 * l + 1] | adj32[2 * (l + 64) + 1]
          | adj32[2 * (l + 128) + 1] | adj32[2 * (l + 192) + 1];
    return (__ballot(v != 0) == 0ull) ? 1 : 0;
}

// ---------------- Fused prep: weights + x->bf16 + hist (one launch) ----------------
__global__ __launch_bounds__(256) void prep_all(
    const float* __restrict__ Wm1, const float* __restrict__ Wm2,
    const float* __restrict__ Wu1, const float* __restrict__ Wu2,
    unsigned short* __restrict__ Wm1t, unsigned short* __restrict__ Wm2t,
    unsigned short* __restrict__ Wu1t, unsigned short* __restrict__ Wu2t,
    const float* __restrict__ x, unsigned short* __restrict__ xbf,
    const void* __restrict__ adj, int* __restrict__ hist)
{
    int bid = blockIdx.x;
    if (bid < PREP_NB) {
        int i = bid * 256 + threadIdx.x;
        if (i < 128 * K1) {
            int n = i / K1, k = i % K1;
            Wm1t[i] = f2bf_rne(Wm1[k * HDIM + n]);
        } else if ((i -= 128 * K1) < 128 * HDIM) {
            int n = i / HDIM, k = i % HDIM;
            Wm2t[i] = f2bf_rne(Wm2[k * HDIM + n]);
        } else if ((i -= 128 * HDIM) < 128 * 256) {
            int n = i / 256, k = i % 256;
            Wu1t[i] = f2bf_rne(Wu1[k * HDIM + n]);
        } else if ((i -= 128 * 256) < 128 * HDIM) {
            int n = i / HDIM, k = i % HDIM;
            Wu2t[i] = f2bf_rne(Wu2[k * HDIM + n]);
        }
    } else if (bid < PREP_NB + X2BF_NB) {
        int i = (bid - PREP_NB) * 256 + threadIdx.x;
        if (i < NNODES * HDIM / 8) {
            const float4* p = (const float4*)(x + i * 8);
            float4 f0 = p[0], f1 = p[1];
            unsigned short s0 = f2bf_rne(f0.x), s1 = f2bf_rne(f0.y), s2 = f2bf_rne(f0.z), s3 = f2bf_rne(f0.w);
            unsigned short s4 = f2bf_rne(f1.x), s5 = f2bf_rne(f1.y), s6 = f2bf_rne(f1.z), s7 = f2bf_rne(f1.w);
            uint4 u;
            u.x = (unsigned)s0 | ((unsigned)s1 << 16);
            u.y = (unsigned)s2 | ((unsigned)s3 << 16);
            u.z = (unsigned)s4 | ((unsigned)s5 << 16);
            u.w = (unsigned)s6 | ((unsigned)s7 << 16);
            *(uint4*)(xbf + i * 8) = u;
        }
    } else {
        int is64 = detect64((const int*)adj);
        int e = (bid - PREP_NB - X2BF_NB) * 256 + threadIdx.x;
        if (e < NEDGES) {
            int r = adj_at(adj, is64, (long long)NEDGES + e);
            atomicAdd(&hist[r], 1);
        }
    }
}

// ---------------- Parallel exclusive scan: block sums, then fused scan ----------------
__global__ __launch_bounds__(256) void scanA_kernel(const int* __restrict__ hist,
                                                    int* __restrict__ bsum)
{
    __shared__ int red[256];
    int i = blockIdx.x * 256 + threadIdx.x;
    int v = (i < NNODES) ? hist[i] : 0;
    red[threadIdx.x] = v;
    __syncthreads();
    for (int d = 128; d > 0; d >>= 1) {
        if (threadIdx.x < d) red[threadIdx.x] += red[threadIdx.x + d];
        __syncthreads();
    }
    if (threadIdx.x == 0) bsum[blockIdx.x] = red[0];
}

// Fused scanB+scanC: each block re-scans the 196 block sums internally.
__global__ __launch_bounds__(256) void scanC_kernel(const int* __restrict__ hist,
                                                    const int* __restrict__ bsum,
                                                    int* __restrict__ cursor)
{
    __shared__ int sb[256];
    __shared__ int s[256];
    int t = threadIdx.x;
    sb[t] = (t < NB) ? bsum[t] : 0;
    int i = blockIdx.x * 256 + t;
    int v = (i < NNODES) ? hist[i] : 0;
    s[t] = v;
    __syncthreads();
    for (int d = 1; d < 256; d <<= 1) {
        int ub = (t >= d) ? sb[t - d] : 0;
        int us = (t >= d) ? s[t - d] : 0;
        __syncthreads();
        sb[t] += ub;
        s[t]  += us;
        __syncthreads();
    }
    int boff = (blockIdx.x == 0) ? 0 : sb[blockIdx.x - 1];
    if (i < NNODES) cursor[i] = boff + s[t] - v;   // exclusive
}

// Packed sorted-edge record: {send, rec, orig_edge, 0} -> one 16B line per edge.
__global__ __launch_bounds__(256) void scatter_kernel(const void* __restrict__ adj,
                                                      int* __restrict__ cursor,
                                                      int4* __restrict__ sEdge)
{
    int is64 = detect64((const int*)adj);
    int e = blockIdx.x * 256 + threadIdx.x;
    if (e < NEDGES) {
        int s = adj_at(adj, is64, e);
        int r = adj_at(adj, is64, (long long)NEDGES + e);
        int pos = atomicAdd(&cursor[r], 1);
        sEdge[pos] = make_int4(s, r, e, 0);
    }
}

// ---------------- Edge kernel: persistent, barrier-free, 2 blocks/CU ----------------
// r4's proven loop body, W1 B-fragments read from GLOBAL (Wm1t, 73.7 KB,
// permanently L2-resident) instead of LDS. LDS 144->68.6 KB -> 2 blocks/CU ->
// 4 waves/SIMD: 2x TLP, which is what hides gather latency (r3-r6 showed ILP
// windows can't at 2 waves/SIMD). No __syncthreads at all. Under the 128-VGPR
// cap this implies, W2 fragments are loaded per-tile just before Layer 2
// (L2-hit reload, r2-proven) instead of held across the whole loop -- a
// persistent 128-reg array would spill through scratch (r2/r5 balloons).
__global__ __launch_bounds__(512, 4) void edge_kernel(
    const unsigned short* __restrict__ xbf, const float* __restrict__ inv,
    const int4* __restrict__ sEdge,
    const unsigned short* __restrict__ Wm1t, const float* __restrict__ bm1,
    const unsigned short* __restrict__ Wm2t, const float* __restrict__ bm2,
    const float* __restrict__ We, const float* __restrict__ be,
    float* __restrict__ aggr)
{
    __shared__ unsigned short s_h[8 * 32 * HSTRIDE];     // 67,584 B (wave-private slices)
    __shared__ int s_recb[8 * 32];                       // 1,024 B

    const int t    = threadIdx.x;
    const int l    = t & 63;
    const int wid  = t >> 6;
    const int l15  = l & 15;
    const int quad = l >> 4;

    float bm1v[8], bm2v[8], wev[8];
    #pragma unroll
    for (int nt = 0; nt < 8; ++nt) {
        bm1v[nt] = bm1[nt * 16 + l15];
        bm2v[nt] = bm2[nt * 16 + l15];
        wev[nt]  = We[nt * 16 + l15];
    }
    const float be0 = be[0];

    // W1/W2 fragment bases for this lane
    const unsigned short* w1base = Wm1t + (unsigned)l15 * K1 + quad * 8;
    const unsigned short* w2base = Wm2t + (unsigned)l15 * HDIM + quad * 8;

    unsigned short* hbuf = s_h + wid * (32 * HSTRIDE);
    int* srec = s_recb + wid * 32;
    const int gwave  = blockIdx.x * 8 + wid;
    const int nwaves = gridDim.x * 8;
    const int t_lo = (int)((long long)gwave * NTILES_E / nwaves);
    const int t_hi = (int)((long long)(gwave + 1) * NTILES_E / nwaves);
    if (t_lo >= t_hi) return;

    // ---- prologue: first tile's indices + send-side gather steps 0..3 ----
    int4 iA = sEdge[t_lo * 32 + l15];
    int4 iB = sEdge[t_lo * 32 + 16 + l15];
    unsigned oS0 = (unsigned)iA.x * HDIM, oR0 = (unsigned)iA.y * HDIM, oI0 = (unsigned)iA.z * NINV;
    unsigned oS1 = (unsigned)iB.x * HDIM, oR1 = (unsigned)iB.y * HDIM, oI1 = (unsigned)iB.z * NINV;

    short8 F[8][2];
    #pragma unroll
    for (int s = 0; s < 4; ++s) {
        F[s][0] = *(const short8*)(xbf + oS0 + s * 32 + quad * 8);
        F[s][1] = *(const short8*)(xbf + oS1 + s * 32 + quad * 8);
    }

    for (int tile = t_lo; tile < t_hi; ++tile) {
        const bool nv = (tile + 1) < t_hi;
        int4 nA, nB;
        if (nv) {                              // next tile's indices (sequential, L2-hot)
            nA = sEdge[(tile + 1) * 32 + l15];
            nB = sEdge[(tile + 1) * 32 + 16 + l15];
        }
        const int re0 = iA.y, re1 = iB.y;      // current tile's rec rows

        // rec-side gathers into F[4..7] + inv raw loads
        #pragma unroll
        for (int s = 0; s < 4; ++s) {
            F[4 + s][0] = *(const short8*)(xbf + oR0 + s * 32 + quad * 8);
            F[4 + s][1] = *(const short8*)(xbf + oR1 + s * 32 + quad * 8);
        }
        float4 I0[2], I1[2];
        {
            const float* p0 = inv + oI0 + quad * 8;
            const float* p1 = inv + oI1 + quad * 8;
            I0[0] = ((const float4*)p0)[0]; I0[1] = ((const float4*)p0)[1];
            I1[0] = ((const float4*)p1)[0]; I1[1] = ((const float4*)p1)[1];
        }

        floatx4 acc[2][8];
        #pragma unroll
        for (int nt = 0; nt < 8; ++nt) {
            acc[0][nt] = (floatx4){bm1v[nt], bm1v[nt], bm1v[nt], bm1v[nt]};
            acc[1][nt] = acc[0][nt];
        }

        // ---- Layer 1: 9 K-steps; B-fragments streamed from L2-resident Wm1t ----
        short8 Fi0, Fi1;
        #pragma unroll
        for (int s = 0; s < 9; ++s) {
            short8 a0, a1;
            if (s < 8) { a0 = F[s][0]; a1 = F[s][1]; }
            else       { a0 = Fi0;     a1 = Fi1;     }
            if (s == 6) {              // convert inv late; loads long since landed
                Fi0 = cvt8(I0[0], I0[1]);
                Fi1 = cvt8(I1[0], I1[1]);
            }
            const unsigned short* wb = w1base + s * 32;
            #pragma unroll
            for (int nt = 0; nt < 8; ++nt) {
                short8 b = *(const short8*)(wb + nt * 16 * K1);
                acc[0][nt] = __builtin_amdgcn_mfma_f32_16x16x32_bf16(a0, b, acc[0][nt], 0, 0, 0);
                acc[1][nt] = __builtin_amdgcn_mfma_f32_16x16x32_bf16(a1, b, acc[1][nt], 0, 0, 0);
            }
        }

        // ---- L1 epilogue: SiLU -> bf16 h into wave-private LDS (no barrier) ----
        #pragma unroll
        for (int m = 0; m < 2; ++m)
            #pragma unroll
            for (int nt = 0; nt < 8; ++nt)
                #pragma unroll
                for (int r = 0; r < 4; ++r) {
                    float hv = silu_f(acc[m][nt][r]);
                    hbuf[(m * 16 + quad * 4 + r) * HSTRIDE + nt * 16 + l15] =
                        (unsigned short)(__float_as_uint(hv) >> 16);
                }

        #pragma unroll
        for (int nt = 0; nt < 8; ++nt) {
            acc[0][nt] = (floatx4){bm2v[nt], bm2v[nt], bm2v[nt], bm2v[nt]};
            acc[1][nt] = acc[0][nt];
        }

        // ---- Layer 2: 4 K-steps; B loaded per-step from L2-resident Wm2t ----
        #pragma unroll
        for (int ks = 0; ks < 4; ++ks) {
            short8 a2[2];
            #pragma unroll
            for (int m = 0; m < 2; ++m) {
                int base = (m * 16 + l15) * HSTRIDE + ks * 32 + quad * 8;
                V4S8 v;
                v.d[0] = *(const int2*)(hbuf + base);
                v.d[1] = *(const int2*)(hbuf + base + 4);
                a2[m] = v.s;
            }
            const unsigned short* wb2 = w2base + ks * 32;
            #pragma unroll
            for (int nt = 0; nt < 8; ++nt) {
                short8 b = *(const short8*)(wb2 + nt * 16 * HDIM);
                acc[0][nt] = __builtin_amdgcn_mfma_f32_16x16x32_bf16(a2[0], b, acc[0][nt], 0, 0, 0);
                acc[1][nt] = __builtin_amdgcn_mfma_f32_16x16x32_bf16(a2[1], b, acc[1][nt], 0, 0, 0);
            }
        }

        // ---- cross-tile warm start: next tile's send gathers issued before
        //      the long VALU epilogue ----
        if (nv) {
            iA = nA; iB = nB;
            oS0 = (unsigned)iA.x * HDIM; oR0 = (unsigned)iA.y * HDIM; oI0 = (unsigned)iA.z * NINV;
            oS1 = (unsigned)iB.x * HDIM; oR1 = (unsigned)iB.y * HDIM; oI1 = (unsigned)iB.z * NINV;
            #pragma unroll
            for (int s = 0; s < 4; ++s) {
                F[s][0] = *(const short8*)(xbf + oS0 + s * 32 + quad * 8);
                F[s][1] = *(const short8*)(xbf + oS1 + s * 32 + quad * 8);
            }
        }

        // ---- Epilogue: SiLU, gate, segmented reduce over sorted rows ----
        #pragma unroll
        for (int m = 0; m < 2; ++m)
            #pragma unroll
            for (int nt = 0; nt < 8; ++nt)
                #pragma unroll
                for (int r = 0; r < 4; ++r)
                    acc[m][nt][r] = silu_f(acc[m][nt][r]);

        float g[2][4];
        #pragma unroll
        for (int m = 0; m < 2; ++m)
            #pragma unroll
            for (int r = 0; r < 4; ++r) {
                float part = 0.f;
                #pragma unroll
                for (int nt = 0; nt < 8; ++nt)
                    part = fmaf(acc[m][nt][r], wev[nt], part);
                part += __shfl_xor(part, 1);
                part += __shfl_xor(part, 2);
                part += __shfl_xor(part, 4);
                part += __shfl_xor(part, 8);
                g[m][r] = 1.0f / (1.0f + __expf(-(part + be0)));
            }

        // publish this tile's 32 rec values (wave-private, no barrier)
        if (quad == 0) { srec[l15] = re0; srec[16 + l15] = re1; }

        // two 64-column passes through the (now dead) h-buffer as f32
        float* fred = (float*)hbuf;
        #pragma unroll
        for (int half = 0; half < 2; ++half) {
            #pragma unroll
            for (int m = 0; m < 2; ++m)
                #pragma unroll
                for (int nt2 = 0; nt2 < 4; ++nt2)
                    #pragma unroll
                    for (int r = 0; r < 4; ++r)
                        fred[(m * 16 + quad * 4 + r) * FSTRIDE + nt2 * 16 + l15] =
                            acc[m][half * 4 + nt2][r] * g[m][r];

            // lane l owns column half*64 + l; rows sorted by rec ->
            // boundary test is wave-uniform (srec[row] broadcast)
            float* dstbase = aggr + half * 64 + l;
            float sum = 0.f;
            int prev = srec[0];
            #pragma unroll
            for (int row = 0; row < 32; ++row) {
                float v = fred[row * FSTRIDE + l];
                int rc = srec[row];
                if (rc != prev) {
                    atomicAdd(dstbase + (unsigned)prev * HDIM, sum);
                    sum = 0.f;
                    prev = rc;
                }
                sum += v;
            }
            atomicAdd(dstbase + (unsigned)prev * HDIM, sum);
        }
    }
}

// ---------------- Node kernel: Wu1 from global -> LDS 33.8 KB -> 4 blocks/CU ----------------
__global__ __launch_bounds__(256, 4) void node_kernel(
    const float* __restrict__ x, const unsigned short* __restrict__ xbf,
    const float* __restrict__ aggr,
    const unsigned short* __restrict__ Wu1t, const float* __restrict__ bu1,
    const unsigned short* __restrict__ Wu2t, const float* __restrict__ bu2,
    float* __restrict__ out)
{
    __shared__ unsigned short s_h[4 * 32 * HSTRIDE];     // 33,792 B

    const int t    = threadIdx.x;
    const int l    = t & 63;
    const int wid  = t >> 6;
    const int l15  = l & 15;
    const int quad = l >> 4;

    float bu1v[8], bu2v[8];
    #pragma unroll
    for (int nt = 0; nt < 8; ++nt) {
        bu1v[nt] = bu1[nt * 16 + l15];
        bu2v[nt] = bu2[nt * 16 + l15];
    }

    const unsigned short* u1base = Wu1t + (unsigned)l15 * 256 + quad * 8;
    const unsigned short* u2base = Wu2t + (unsigned)l15 * HDIM + quad * 8;

    unsigned short* hbuf = s_h + wid * (32 * HSTRIDE);
    const int nwaves = gridDim.x * 4;

    for (int tile = blockIdx.x * 4 + wid; tile < NTILES_N; tile += nwaves) {
        const int n0 = tile * 32;

        unsigned offX[2];
        #pragma unroll
        for (int m = 0; m < 2; ++m) {
            int row = n0 + m * 16 + l15;
            if (row >= NNODES) row = NNODES - 1;
            offX[m] = (unsigned)row * HDIM;
        }

        floatx4 acc[2][8];
        #pragma unroll
        for (int nt = 0; nt < 8; ++nt) {
            acc[0][nt] = (floatx4){bu1v[nt], bu1v[nt], bu1v[nt], bu1v[nt]};
            acc[1][nt] = acc[0][nt];
        }

        // Layer 1: K=256 ([x | aggr]), 8 K-steps; x side from xbf; B from L2-resident Wu1t
        #pragma unroll
        for (int s = 0; s < 8; ++s) {
            short8 a[2];
            #pragma unroll
            for (int m = 0; m < 2; ++m) {
                if (s < 4) {
                    a[m] = *(const short8*)(xbf + offX[m] + s * 32 + quad * 8);
                } else {
                    const float* p = aggr + offX[m] + (s - 4) * 32 + quad * 8;
                    a[m] = cvt8(((const float4*)p)[0], ((const float4*)p)[1]);
                }
            }
            const unsigned short* wb = u1base + s * 32;
            #pragma unroll
            for (int nt = 0; nt < 8; ++nt) {
                short8 b = *(const short8*)(wb + nt * 16 * 256);
                acc[0][nt] = __builtin_amdgcn_mfma_f32_16x16x32_bf16(a[0], b, acc[0][nt], 0, 0, 0);
                acc[1][nt] = __builtin_amdgcn_mfma_f32_16x16x32_bf16(a[1], b, acc[1][nt], 0, 0, 0);
            }
        }

        #pragma unroll
        for (int m = 0; m < 2; ++m)
            #pragma unroll
            for (int nt = 0; nt < 8; ++nt)
                #pragma unroll
                for (int r = 0; r < 4; ++r) {
                    float hv = silu_f(acc[m][nt][r]);
                    hbuf[(m * 16 + quad * 4 + r) * HSTRIDE + nt * 16 + l15] =
                        (unsigned short)(__float_as_uint(hv) >> 16);
                }

        #pragma unroll
        for (int nt = 0; nt < 8; ++nt) {
            acc[0][nt] = (floatx4){bu2v[nt], bu2v[nt], bu2v[nt], bu2v[nt]};
            acc[1][nt] = acc[0][nt];
        }

        // Layer 2: B loaded per-step from L2-resident Wu2t
        #pragma unroll
        for (int ks = 0; ks < 4; ++ks) {
            short8 a2[2];
            #pragma unroll
            for (int m = 0; m < 2; ++m) {
                int base = (m * 16 + l15) * HSTRIDE + ks * 32 + quad * 8;
                V4S8 v;
                v.d[0] = *(const int2*)(hbuf + base);
                v.d[1] = *(const int2*)(hbuf + base + 4);
                a2[m] = v.s;
            }
            const unsigned short* wb2 = u2base + ks * 32;
            #pragma unroll
            for (int nt = 0; nt < 8; ++nt) {
                short8 b = *(const short8*)(wb2 + nt * 16 * HDIM);
                acc[0][nt] = __builtin_amdgcn_mfma_f32_16x16x32_bf16(a2[0], b, acc[0][nt], 0, 0, 0);
                acc[1][nt] = __builtin_amdgcn_mfma_f32_16x16x32_bf16(a2[1], b, acc[1][nt], 0, 0, 0);
            }
        }

        // Residual + store (no activation after layer 2)
        #pragma unroll
        for (int m = 0; m < 2; ++m)
            #pragma unroll
            for (int r = 0; r < 4; ++r) {
                int row = n0 + m * 16 + quad * 4 + r;
                if (row < NNODES) {
                    #pragma unroll
                    for (int nt = 0; nt < 8; ++nt) {
                        int col = nt * 16 + l15;
                        out[(long long)row * HDIM + col] = x[(long long)row * HDIM + col] + acc[m][nt][r];
                    }
                }
            }
    }
}

extern "C" void kernel_launch(void* const* d_in, const int* in_sizes, int n_in,
                              void* d_out, int out_size, void* d_ws, size_t ws_size,
                              hipStream_t stream)
{
    const float* x   = (const float*)d_in[0];
    const void*  adj = d_in[1];
    const float* inv = (const float*)d_in[2];
    const float* Wm1 = (const float*)d_in[3];
    const float* bm1 = (const float*)d_in[4];
    const float* Wm2 = (const float*)d_in[5];
    const float* bm2 = (const float*)d_in[6];
    const float* We  = (const float*)d_in[7];
    const float* be  = (const float*)d_in[8];
    const float* Wu1 = (const float*)d_in[9];
    const float* bu1 = (const float*)d_in[10];
    const float* Wu2 = (const float*)d_in[11];
    const float* bu2 = (const float*)d_in[12];
    float* out = (float*)d_out;

    char* ws = (char*)d_ws;
    float* aggr = (float*)ws;
    size_t off = (size_t)NNODES * HDIM * 4;                              // 25,600,000
    int* hist   = (int*)(ws + off);          off += (size_t)NNODES * 4;  // contiguous with aggr -> one memset
    unsigned short* Wm1t = (unsigned short*)(ws + off);  off += 128 * K1 * 2;
    unsigned short* Wm2t = (unsigned short*)(ws + off);  off += 128 * HDIM * 2;
    unsigned short* Wu1t = (unsigned short*)(ws + off);  off += 128 * 256 * 2;
    unsigned short* Wu2t = (unsigned short*)(ws + off);  off += 128 * HDIM * 2;
    off = (off + 63) & ~(size_t)63;
    unsigned short* xbf = (unsigned short*)(ws + off);   off += (size_t)NNODES * HDIM * 2;
    int* cursor = (int*)(ws + off);          off += (size_t)NNODES * 4;
    int* bsum   = (int*)(ws + off);          off += 1024;
    off = (off + 63) & ~(size_t)63;
    int4* sEdge = (int4*)(ws + off);         off += (size_t)NEDGES * 16;

    hipMemsetAsync(aggr, 0, (size_t)(NNODES * HDIM + NNODES) * sizeof(float), stream);
    prep_all<<<PREP_NB + X2BF_NB + HIST_NB, 256, 0, stream>>>(
        Wm1, Wm2, Wu1, Wu2, Wm1t, Wm2t, Wu1t, Wu2t, x, xbf, adj, hist);
    scanA_kernel<<<NB, 256, 0, stream>>>(hist, bsum);
    scanC_kernel<<<NB, 256, 0, stream>>>(hist, bsum, cursor);
    scatter_kernel<<<(NEDGES + 255) / 256, 256, 0, stream>>>(adj, cursor, sEdge);
    edge_kernel<<<512, 512, 0, stream>>>(xbf, inv, sEdge,
                                         Wm1t, bm1, Wm2t, bm2, We, be, aggr);
    node_kernel<<<(NTILES_N + 3) / 4, 256, 0, stream>>>(x, xbf, aggr,
                                                        Wu1t, bu1, Wu2t, bu2, out);
}

// Round 9
// 1405.714 us; speedup vs baseline: 1.2611x; 1.2611x over previous
//
#include <hip/hip_runtime.h>
#include <math.h>

#define NNODES 50000
#define NEDGES 800000
#define HDIM 128
#define NINV 32
#define K1 288            // 2H + NINV
#define NTILES_E 25000    // NEDGES / 32
#define NTILES_N 1563     // ceil(NNODES / 32)
#define NB 196            // scan blocks: 196*256 = 50176 >= NNODES

#define PREP_NB 400       // 102400 weight elems / 256
#define X2BF_NB 3125      // 800000 groups of 8 / 256
#define HIST_NB 3125      // 800000 edges / 256

#define HSTRIDE 132       // h-buffer row stride in ushorts (128+4): 66 dw == 2 mod 32 -> u16 writes 2-way free
#define FSTRIDE 66        // same buffer viewed as f32: 66 dw/row (64 cols + 2 pad)

typedef float floatx4 __attribute__((ext_vector_type(4)));
typedef short short8  __attribute__((ext_vector_type(8)));

union V4S8 { uint4 u; short8 s; int2 d[2]; };

__device__ __forceinline__ float silu_f(float z) { return z / (1.0f + __expf(-z)); }

__device__ __forceinline__ unsigned short f2bf_rne(float f) {
    unsigned u = __float_as_uint(f);
    u += 0x7fffu + ((u >> 16) & 1u);
    return (unsigned short)(u >> 16);
}

// pack hi16(bf-truncate) of two floats into one dword: [lo | hi<<16]
__device__ __forceinline__ unsigned pk_bf(float hi, float lo) {
    return __builtin_amdgcn_perm(__float_as_uint(hi), __float_as_uint(lo), 0x07060302);
}

__device__ __forceinline__ short8 cvt8(float4 f0, float4 f1) {
    V4S8 v;
    v.u.x = pk_bf(f0.y, f0.x);
    v.u.y = pk_bf(f0.w, f0.z);
    v.u.z = pk_bf(f1.y, f1.x);
    v.u.w = pk_bf(f1.w, f1.z);
    return v.s;
}

__device__ __forceinline__ int adj_at(const void* adj, int is64, long long pos) {
    if (is64) return (int)((const long long*)adj)[pos];
    return ((const int*)adj)[pos];
}

// Per-wave inline int64-vs-int32 detection: odd dwords of the first 256
// qword-slots are all zero iff adj is int64 (indices < 2^31).
__device__ __forceinline__ int detect64(const int* __restrict__ adj32) {
    int l = threadIdx.x & 63;
    int v = adj32[2 * l + 1] | adj32[2 * (l + 64) + 1]
          | adj32[2 * (l + 128) + 1] | adj32[2 * (l + 192) + 1];
    return (__ballot(v != 0) == 0ull) ? 1 : 0;
}

// ---------------- Fused prep: weights + x->bf16 + hist (one launch) ----------------
__global__ __launch_bounds__(256) void prep_all(
    const float* __restrict__ Wm1, const float* __restrict__ Wm2,
    const float* __restrict__ Wu1, const float* __restrict__ Wu2,
    unsigned short* __restrict__ Wm1t, unsigned short* __restrict__ Wm2t,
    unsigned short* __restrict__ Wu1t, unsigned short* __restrict__ Wu2t,
    const float* __restrict__ x, unsigned short* __restrict__ xbf,
    const void* __restrict__ adj, int* __restrict__ hist)
{
    int bid = blockIdx.x;
    if (bid < PREP_NB) {
        int i = bid * 256 + threadIdx.x;
        if (i < 128 * K1) {
            int n = i / K1, k = i % K1;
            Wm1t[i] = f2bf_rne(Wm1[k * HDIM + n]);
        } else if ((i -= 128 * K1) < 128 * HDIM) {
            int n = i / HDIM, k = i % HDIM;
            Wm2t[i] = f2bf_rne(Wm2[k * HDIM + n]);
        } else if ((i -= 128 * HDIM) < 128 * 256) {
            int n = i / 256, k = i % 256;
            Wu1t[i] = f2bf_rne(Wu1[k * HDIM + n]);
        } else if ((i -= 128 * 256) < 128 * HDIM) {
            int n = i / HDIM, k = i % HDIM;
            Wu2t[i] = f2bf_rne(Wu2[k * HDIM + n]);
        }
    } else if (bid < PREP_NB + X2BF_NB) {
        int i = (bid - PREP_NB) * 256 + threadIdx.x;
        if (i < NNODES * HDIM / 8) {
            const float4* p = (const float4*)(x + i * 8);
            float4 f0 = p[0], f1 = p[1];
            unsigned short s0 = f2bf_rne(f0.x), s1 = f2bf_rne(f0.y), s2 = f2bf_rne(f0.z), s3 = f2bf_rne(f0.w);
            unsigned short s4 = f2bf_rne(f1.x), s5 = f2bf_rne(f1.y), s6 = f2bf_rne(f1.z), s7 = f2bf_rne(f1.w);
            uint4 u;
            u.x = (unsigned)s0 | ((unsigned)s1 << 16);
            u.y = (unsigned)s2 | ((unsigned)s3 << 16);
            u.z = (unsigned)s4 | ((unsigned)s5 << 16);
            u.w = (unsigned)s6 | ((unsigned)s7 << 16);
            *(uint4*)(xbf + i * 8) = u;
        }
    } else {
        int is64 = detect64((const int*)adj);
        int e = (bid - PREP_NB - X2BF_NB) * 256 + threadIdx.x;
        if (e < NEDGES) {
            int r = adj_at(adj, is64, (long long)NEDGES + e);
            atomicAdd(&hist[r], 1);
        }
    }
}

// ---------------- Parallel exclusive scan: block sums, then fused scan ----------------
__global__ __launch_bounds__(256) void scanA_kernel(const int* __restrict__ hist,
                                                    int* __restrict__ bsum)
{
    __shared__ int red[256];
    int i = blockIdx.x * 256 + threadIdx.x;
    int v = (i < NNODES) ? hist[i] : 0;
    red[threadIdx.x] = v;
    __syncthreads();
    for (int d = 128; d > 0; d >>= 1) {
        if (threadIdx.x < d) red[threadIdx.x] += red[threadIdx.x + d];
        __syncthreads();
    }
    if (threadIdx.x == 0) bsum[blockIdx.x] = red[0];
}

// Fused scanB+scanC: each block re-scans the 196 block sums internally.
__global__ __launch_bounds__(256) void scanC_kernel(const int* __restrict__ hist,
                                                    const int* __restrict__ bsum,
                                                    int* __restrict__ cursor)
{
    __shared__ int sb[256];
    __shared__ int s[256];
    int t = threadIdx.x;
    sb[t] = (t < NB) ? bsum[t] : 0;
    int i = blockIdx.x * 256 + t;
    int v = (i < NNODES) ? hist[i] : 0;
    s[t] = v;
    __syncthreads();
    for (int d = 1; d < 256; d <<= 1) {
        int ub = (t >= d) ? sb[t - d] : 0;
        int us = (t >= d) ? s[t - d] : 0;
        __syncthreads();
        sb[t] += ub;
        s[t]  += us;
        __syncthreads();
    }
    int boff = (blockIdx.x == 0) ? 0 : sb[blockIdx.x - 1];
    if (i < NNODES) cursor[i] = boff + s[t] - v;   // exclusive
}

// Packed sorted-edge record: {send, rec, orig_edge, 0} -> one 16B line per edge.
__global__ __launch_bounds__(256) void scatter_kernel(const void* __restrict__ adj,
                                                      int* __restrict__ cursor,
                                                      int4* __restrict__ sEdge)
{
    int is64 = detect64((const int*)adj);
    int e = blockIdx.x * 256 + threadIdx.x;
    if (e < NEDGES) {
        int s = adj_at(adj, is64, e);
        int r = adj_at(adj, is64, (long long)NEDGES + e);
        int pos = atomicAdd(&cursor[r], 1);
        sEdge[pos] = make_int4(s, r, e, 0);
    }
}

// ---------------- Edge kernel: persistent, barrier-free, 2 blocks/CU ----------------
// W1/W2 B-fragments streamed from GLOBAL (L2-resident Wm1t/Wm2t) instead of LDS.
// LDS 144->68.6 KB -> 2 blocks/CU -> 4 waves/SIMD (2x TLP to hide gather latency).
// __launch_bounds__ 2nd arg acts as CUDA min-BLOCKS-per-CU on this toolchain
// (measured: (512,1)->128 regs chosen, (512,2)->128 cap, (512,4)->64 cap+spill
// disaster in r8). (512,2) = 2 blocks/CU = 4 waves/SIMD = 128-reg cap, which the
// r4-proven loop body fits without spilling.
__global__ __launch_bounds__(512, 2) void edge_kernel(
    const unsigned short* __restrict__ xbf, const float* __restrict__ inv,
    const int4* __restrict__ sEdge,
    const unsigned short* __restrict__ Wm1t, const float* __restrict__ bm1,
    const unsigned short* __restrict__ Wm2t, const float* __restrict__ bm2,
    const float* __restrict__ We, const float* __restrict__ be,
    float* __restrict__ aggr)
{
    __shared__ unsigned short s_h[8 * 32 * HSTRIDE];     // 67,584 B (wave-private slices)
    __shared__ int s_recb[8 * 32];                       // 1,024 B

    const int t    = threadIdx.x;
    const int l    = t & 63;
    const int wid  = t >> 6;
    const int l15  = l & 15;
    const int quad = l >> 4;

    float bm1v[8], bm2v[8], wev[8];
    #pragma unroll
    for (int nt = 0; nt < 8; ++nt) {
        bm1v[nt] = bm1[nt * 16 + l15];
        bm2v[nt] = bm2[nt * 16 + l15];
        wev[nt]  = We[nt * 16 + l15];
    }
    const float be0 = be[0];

    // W1/W2 fragment bases for this lane
    const unsigned short* w1base = Wm1t + (unsigned)l15 * K1 + quad * 8;
    const unsigned short* w2base = Wm2t + (unsigned)l15 * HDIM + quad * 8;

    unsigned short* hbuf = s_h + wid * (32 * HSTRIDE);
    int* srec = s_recb + wid * 32;
    const int gwave  = blockIdx.x * 8 + wid;
    const int nwaves = gridDim.x * 8;
    const int t_lo = (int)((long long)gwave * NTILES_E / nwaves);
    const int t_hi = (int)((long long)(gwave + 1) * NTILES_E / nwaves);
    if (t_lo >= t_hi) return;

    // ---- prologue: first tile's indices + send-side gather steps 0..3 ----
    int4 iA = sEdge[t_lo * 32 + l15];
    int4 iB = sEdge[t_lo * 32 + 16 + l15];
    unsigned oS0 = (unsigned)iA.x * HDIM, oR0 = (unsigned)iA.y * HDIM, oI0 = (unsigned)iA.z * NINV;
    unsigned oS1 = (unsigned)iB.x * HDIM, oR1 = (unsigned)iB.y * HDIM, oI1 = (unsigned)iB.z * NINV;

    short8 F[8][2];
    #pragma unroll
    for (int s = 0; s < 4; ++s) {
        F[s][0] = *(const short8*)(xbf + oS0 + s * 32 + quad * 8);
        F[s][1] = *(const short8*)(xbf + oS1 + s * 32 + quad * 8);
    }

    for (int tile = t_lo; tile < t_hi; ++tile) {
        const bool nv = (tile + 1) < t_hi;
        int4 nA, nB;
        if (nv) {                              // next tile's indices (sequential, L2-hot)
            nA = sEdge[(tile + 1) * 32 + l15];
            nB = sEdge[(tile + 1) * 32 + 16 + l15];
        }
        const int re0 = iA.y, re1 = iB.y;      // current tile's rec rows

        // rec-side gathers into F[4..7] + inv raw loads
        #pragma unroll
        for (int s = 0; s < 4; ++s) {
            F[4 + s][0] = *(const short8*)(xbf + oR0 + s * 32 + quad * 8);
            F[4 + s][1] = *(const short8*)(xbf + oR1 + s * 32 + quad * 8);
        }
        float4 I0[2], I1[2];
        {
            const float* p0 = inv + oI0 + quad * 8;
            const float* p1 = inv + oI1 + quad * 8;
            I0[0] = ((const float4*)p0)[0]; I0[1] = ((const float4*)p0)[1];
            I1[0] = ((const float4*)p1)[0]; I1[1] = ((const float4*)p1)[1];
        }

        floatx4 acc[2][8];
        #pragma unroll
        for (int nt = 0; nt < 8; ++nt) {
            acc[0][nt] = (floatx4){bm1v[nt], bm1v[nt], bm1v[nt], bm1v[nt]};
            acc[1][nt] = acc[0][nt];
        }

        // ---- Layer 1: 9 K-steps; B-fragments streamed from L2-resident Wm1t ----
        short8 Fi0, Fi1;
        #pragma unroll
        for (int s = 0; s < 9; ++s) {
            short8 a0, a1;
            if (s < 8) { a0 = F[s][0]; a1 = F[s][1]; }
            else       { a0 = Fi0;     a1 = Fi1;     }
            if (s == 6) {              // convert inv late; loads long since landed
                Fi0 = cvt8(I0[0], I0[1]);
                Fi1 = cvt8(I1[0], I1[1]);
            }
            const unsigned short* wb = w1base + s * 32;
            #pragma unroll
            for (int nt = 0; nt < 8; ++nt) {
                short8 b = *(const short8*)(wb + nt * 16 * K1);
                acc[0][nt] = __builtin_amdgcn_mfma_f32_16x16x32_bf16(a0, b, acc[0][nt], 0, 0, 0);
                acc[1][nt] = __builtin_amdgcn_mfma_f32_16x16x32_bf16(a1, b, acc[1][nt], 0, 0, 0);
            }
        }

        // ---- L1 epilogue: SiLU -> bf16 h into wave-private LDS (no barrier) ----
        #pragma unroll
        for (int m = 0; m < 2; ++m)
            #pragma unroll
            for (int nt = 0; nt < 8; ++nt)
                #pragma unroll
                for (int r = 0; r < 4; ++r) {
                    float hv = silu_f(acc[m][nt][r]);
                    hbuf[(m * 16 + quad * 4 + r) * HSTRIDE + nt * 16 + l15] =
                        (unsigned short)(__float_as_uint(hv) >> 16);
                }

        #pragma unroll
        for (int nt = 0; nt < 8; ++nt) {
            acc[0][nt] = (floatx4){bm2v[nt], bm2v[nt], bm2v[nt], bm2v[nt]};
            acc[1][nt] = acc[0][nt];
        }

        // ---- Layer 2: 4 K-steps; B loaded per-step from L2-resident Wm2t ----
        #pragma unroll
        for (int ks = 0; ks < 4; ++ks) {
            short8 a2[2];
            #pragma unroll
            for (int m = 0; m < 2; ++m) {
                int base = (m * 16 + l15) * HSTRIDE + ks * 32 + quad * 8;
                V4S8 v;
                v.d[0] = *(const int2*)(hbuf + base);
                v.d[1] = *(const int2*)(hbuf + base + 4);
                a2[m] = v.s;
            }
            const unsigned short* wb2 = w2base + ks * 32;
            #pragma unroll
            for (int nt = 0; nt < 8; ++nt) {
                short8 b = *(const short8*)(wb2 + nt * 16 * HDIM);
                acc[0][nt] = __builtin_amdgcn_mfma_f32_16x16x32_bf16(a2[0], b, acc[0][nt], 0, 0, 0);
                acc[1][nt] = __builtin_amdgcn_mfma_f32_16x16x32_bf16(a2[1], b, acc[1][nt], 0, 0, 0);
            }
        }

        // ---- cross-tile warm start: next tile's send gathers issued before
        //      the long VALU epilogue ----
        if (nv) {
            iA = nA; iB = nB;
            oS0 = (unsigned)iA.x * HDIM; oR0 = (unsigned)iA.y * HDIM; oI0 = (unsigned)iA.z * NINV;
            oS1 = (unsigned)iB.x * HDIM; oR1 = (unsigned)iB.y * HDIM; oI1 = (unsigned)iB.z * NINV;
            #pragma unroll
            for (int s = 0; s < 4; ++s) {
                F[s][0] = *(const short8*)(xbf + oS0 + s * 32 + quad * 8);
                F[s][1] = *(const short8*)(xbf + oS1 + s * 32 + quad * 8);
            }
        }

        // ---- Epilogue: SiLU, gate, segmented reduce over sorted rows ----
        #pragma unroll
        for (int m = 0; m < 2; ++m)
            #pragma unroll
            for (int nt = 0; nt < 8; ++nt)
                #pragma unroll
                for (int r = 0; r < 4; ++r)
                    acc[m][nt][r] = silu_f(acc[m][nt][r]);

        float g[2][4];
        #pragma unroll
        for (int m = 0; m < 2; ++m)
            #pragma unroll
            for (int r = 0; r < 4; ++r) {
                float part = 0.f;
                #pragma unroll
                for (int nt = 0; nt < 8; ++nt)
                    part = fmaf(acc[m][nt][r], wev[nt], part);
                part += __shfl_xor(part, 1);
                part += __shfl_xor(part, 2);
                part += __shfl_xor(part, 4);
                part += __shfl_xor(part, 8);
                g[m][r] = 1.0f / (1.0f + __expf(-(part + be0)));
            }

        // publish this tile's 32 rec values (wave-private, no barrier)
        if (quad == 0) { srec[l15] = re0; srec[16 + l15] = re1; }

        // two 64-column passes through the (now dead) h-buffer as f32
        float* fred = (float*)hbuf;
        #pragma unroll
        for (int half = 0; half < 2; ++half) {
            #pragma unroll
            for (int m = 0; m < 2; ++m)
                #pragma unroll
                for (int nt2 = 0; nt2 < 4; ++nt2)
                    #pragma unroll
                    for (int r = 0; r < 4; ++r)
                        fred[(m * 16 + quad * 4 + r) * FSTRIDE + nt2 * 16 + l15] =
                            acc[m][half * 4 + nt2][r] * g[m][r];

            // lane l owns column half*64 + l; rows sorted by rec ->
            // boundary test is wave-uniform (srec[row] broadcast)
            float* dstbase = aggr + half * 64 + l;
            float sum = 0.f;
            int prev = srec[0];
            #pragma unroll
            for (int row = 0; row < 32; ++row) {
                float v = fred[row * FSTRIDE + l];
                int rc = srec[row];
                if (rc != prev) {
                    atomicAdd(dstbase + (unsigned)prev * HDIM, sum);
                    sum = 0.f;
                    prev = rc;
                }
                sum += v;
            }
            atomicAdd(dstbase + (unsigned)prev * HDIM, sum);
        }
    }
}

// ---------------- Node kernel: Wu1 from global -> LDS 33.8 KB -> 4 blocks/CU ----------------
// (256,4) = 4 blocks/CU = 16 waves/CU = 4 waves/SIMD -> 128-reg cap; node's
// live set (~100 regs) fits.
__global__ __launch_bounds__(256, 4) void node_kernel(
    const float* __restrict__ x, const unsigned short* __restrict__ xbf,
    const float* __restrict__ aggr,
    const unsigned short* __restrict__ Wu1t, const float* __restrict__ bu1,
    const unsigned short* __restrict__ Wu2t, const float* __restrict__ bu2,
    float* __restrict__ out)
{
    __shared__ unsigned short s_h[4 * 32 * HSTRIDE];     // 33,792 B

    const int t    = threadIdx.x;
    const int l    = t & 63;
    const int wid  = t >> 6;
    const int l15  = l & 15;
    const int quad = l >> 4;

    float bu1v[8], bu2v[8];
    #pragma unroll
    for (int nt = 0; nt < 8; ++nt) {
        bu1v[nt] = bu1[nt * 16 + l15];
        bu2v[nt] = bu2[nt * 16 + l15];
    }

    const unsigned short* u1base = Wu1t + (unsigned)l15 * 256 + quad * 8;
    const unsigned short* u2base = Wu2t + (unsigned)l15 * HDIM + quad * 8;

    unsigned short* hbuf = s_h + wid * (32 * HSTRIDE);
    const int nwaves = gridDim.x * 4;

    for (int tile = blockIdx.x * 4 + wid; tile < NTILES_N; tile += nwaves) {
        const int n0 = tile * 32;

        unsigned offX[2];
        #pragma unroll
        for (int m = 0; m < 2; ++m) {
            int row = n0 + m * 16 + l15;
            if (row >= NNODES) row = NNODES - 1;
            offX[m] = (unsigned)row * HDIM;
        }

        floatx4 acc[2][8];
        #pragma unroll
        for (int nt = 0; nt < 8; ++nt) {
            acc[0][nt] = (floatx4){bu1v[nt], bu1v[nt], bu1v[nt], bu1v[nt]};
            acc[1][nt] = acc[0][nt];
        }

        // Layer 1: K=256 ([x | aggr]), 8 K-steps; x side from xbf; B from L2-resident Wu1t
        #pragma unroll
        for (int s = 0; s < 8; ++s) {
            short8 a[2];
            #pragma unroll
            for (int m = 0; m < 2; ++m) {
                if (s < 4) {
                    a[m] = *(const short8*)(xbf + offX[m] + s * 32 + quad * 8);
                } else {
                    const float* p = aggr + offX[m] + (s - 4) * 32 + quad * 8;
                    a[m] = cvt8(((const float4*)p)[0], ((const float4*)p)[1]);
                }
            }
            const unsigned short* wb = u1base + s * 32;
            #pragma unroll
            for (int nt = 0; nt < 8; ++nt) {
                short8 b = *(const short8*)(wb + nt * 16 * 256);
                acc[0][nt] = __builtin_amdgcn_mfma_f32_16x16x32_bf16(a[0], b, acc[0][nt], 0, 0, 0);
                acc[1][nt] = __builtin_amdgcn_mfma_f32_16x16x32_bf16(a[1], b, acc[1][nt], 0, 0, 0);
            }
        }

        #pragma unroll
        for (int m = 0; m < 2; ++m)
            #pragma unroll
            for (int nt = 0; nt < 8; ++nt)
                #pragma unroll
                for (int r = 0; r < 4; ++r) {
                    float hv = silu_f(acc[m][nt][r]);
                    hbuf[(m * 16 + quad * 4 + r) * HSTRIDE + nt * 16 + l15] =
                        (unsigned short)(__float_as_uint(hv) >> 16);
                }

        #pragma unroll
        for (int nt = 0; nt < 8; ++nt) {
            acc[0][nt] = (floatx4){bu2v[nt], bu2v[nt], bu2v[nt], bu2v[nt]};
            acc[1][nt] = acc[0][nt];
        }

        // Layer 2: B loaded per-step from L2-resident Wu2t
        #pragma unroll
        for (int ks = 0; ks < 4; ++ks) {
            short8 a2[2];
            #pragma unroll
            for (int m = 0; m < 2; ++m) {
                int base = (m * 16 + l15) * HSTRIDE + ks * 32 + quad * 8;
                V4S8 v;
                v.d[0] = *(const int2*)(hbuf + base);
                v.d[1] = *(const int2*)(hbuf + base + 4);
                a2[m] = v.s;
            }
            const unsigned short* wb2 = u2base + ks * 32;
            #pragma unroll
            for (int nt = 0; nt < 8; ++nt) {
                short8 b = *(const short8*)(wb2 + nt * 16 * HDIM);
                acc[0][nt] = __builtin_amdgcn_mfma_f32_16x16x32_bf16(a2[0], b, acc[0][nt], 0, 0, 0);
                acc[1][nt] = __builtin_amdgcn_mfma_f32_16x16x32_bf16(a2[1], b, acc[1][nt], 0, 0, 0);
            }
        }

        // Residual + store (no activation after layer 2)
        #pragma unroll
        for (int m = 0; m < 2; ++m)
            #pragma unroll
            for (int r = 0; r < 4; ++r) {
                int row = n0 + m * 16 + quad * 4 + r;
                if (row < NNODES) {
                    #pragma unroll
                    for (int nt = 0; nt < 8; ++nt) {
                        int col = nt * 16 + l15;
                        out[(long long)row * HDIM + col] = x[(long long)row * HDIM + col] + acc[m][nt][r];
                    }
                }
            }
    }
}

extern "C" void kernel_launch(void* const* d_in, const int* in_sizes, int n_in,
                              void* d_out, int out_size, void* d_ws, size_t ws_size,
                              hipStream_t stream)
{
    const float* x   = (const float*)d_in[0];
    const void*  adj = d_in[1];
    const float* inv = (const float*)d_in[2];
    const float* Wm1 = (const float*)d_in[3];
    const float* bm1 = (const float*)d_in[4];
    const float* Wm2 = (const float*)d_in[5];
    const float* bm2 = (const float*)d_in[6];
    const float* We  = (const float*)d_in[7];
    const float* be  = (const float*)d_in[8];
    const float* Wu1 = (const float*)d_in[9];
    const float* bu1 = (const float*)d_in[10];
    const float* Wu2 = (const float*)d_in[11];
    const float* bu2 = (const float*)d_in[12];
    float* out = (float*)d_out;

    char* ws = (char*)d_ws;
    float* aggr = (float*)ws;
    size_t off = (size_t)NNODES * HDIM * 4;                              // 25,600,000
    int* hist   = (int*)(ws + off);          off += (size_t)NNODES * 4;  // contiguous with aggr -> one memset
    unsigned short* Wm1t = (unsigned short*)(ws + off);  off += 128 * K1 * 2;
    unsigned short* Wm2t = (unsigned short*)(ws + off);  off += 128 * HDIM * 2;
    unsigned short* Wu1t = (unsigned short*)(ws + off);  off += 128 * 256 * 2;
    unsigned short* Wu2t = (unsigned short*)(ws + off);  off += 128 * HDIM * 2;
    off = (off + 63) & ~(size_t)63;
    unsigned short* xbf = (unsigned short*)(ws + off);   off += (size_t)NNODES * HDIM * 2;
    int* cursor = (int*)(ws + off);          off += (size_t)NNODES * 4;
    int* bsum   = (int*)(ws + off);          off += 1024;
    off = (off + 63) & ~(size_t)63;
    int4* sEdge = (int4*)(ws + off);         off += (size_t)NEDGES * 16;

    hipMemsetAsync(aggr, 0, (size_t)(NNODES * HDIM + NNODES) * sizeof(float), stream);
    prep_all<<<PREP_NB + X2BF_NB + HIST_NB, 256, 0, stream>>>(
        Wm1, Wm2, Wu1, Wu2, Wm1t, Wm2t, Wu1t, Wu2t, x, xbf, adj, hist);
    scanA_kernel<<<NB, 256, 0, stream>>>(hist, bsum);
    scanC_kernel<<<NB, 256, 0, stream>>>(hist, bsum, cursor);
    scatter_kernel<<<(NEDGES + 255) / 256, 256, 0, stream>>>(adj, cursor, sEdge);
    edge_kernel<<<512, 512, 0, stream>>>(xbf, inv, sEdge,
                                         Wm1t, bm1, Wm2t, bm2, We, be, aggr);
    node_kernel<<<(NTILES_N + 3) / 4, 256, 0, stream>>>(x, xbf, aggr,
                                                        Wu1t, bu1, Wu2t, bu2, out);
}

// Round 10
// 601.070 us; speedup vs baseline: 2.9493x; 2.3387x over previous
//
#include <hip/hip_runtime.h>
#include <math.h>

#define NNODES 50000
#define NEDGES 800000
#define HDIM 128
#define NINV 32
#define K1 288            // 2H + NINV
#define NTILES_E 25000    // NEDGES / 32
#define NTILES_N 1563     // ceil(NNODES / 32)
#define NB 196            // scan blocks: 196*256 = 50176 >= NNODES

#define PREP_NB 400       // 102400 weight elems / 256
#define X2BF_NB 3125      // 800000 groups of 8 / 256
#define HIST_NB 3125      // 800000 edges / 256

#define W1STRIDE 296      // ushorts per W1 LDS row (288+8): 148 dw == 20 mod 32 -> uniform banks, 16B aligned
#define U1STRIDE 264      // ushorts per Wu1 LDS row (256+8): 132 dw == 4 mod 32, 16B aligned
#define HSTRIDE 132       // h-buffer row stride in ushorts (128+4): 66 dw == 2 mod 32 -> u16 writes 2-way free
#define FSTRIDE 66        // same buffer viewed as f32: 66 dw/row (64 cols + 2 pad)

typedef float floatx4 __attribute__((ext_vector_type(4)));
typedef int   intx4   __attribute__((ext_vector_type(4)));
typedef short short8  __attribute__((ext_vector_type(8)));

union V4S8 { uint4 u; short8 s; int2 d[2]; };

__device__ __forceinline__ float silu_f(float z) { return z / (1.0f + __expf(-z)); }

__device__ __forceinline__ unsigned short f2bf_rne(float f) {
    unsigned u = __float_as_uint(f);
    u += 0x7fffu + ((u >> 16) & 1u);
    return (unsigned short)(u >> 16);
}

// pack hi16(bf-truncate) of two floats into one dword: [lo | hi<<16]
__device__ __forceinline__ unsigned pk_bf(float hi, float lo) {
    return __builtin_amdgcn_perm(__float_as_uint(hi), __float_as_uint(lo), 0x07060302);
}

__device__ __forceinline__ short8 cvt8(float4 f0, float4 f1) {
    V4S8 v;
    v.u.x = pk_bf(f0.y, f0.x);
    v.u.y = pk_bf(f0.w, f0.z);
    v.u.z = pk_bf(f1.y, f1.x);
    v.u.w = pk_bf(f1.w, f1.z);
    return v.s;
}

// Non-temporal 16B loads: keep streaming, zero-reuse data (inv, sEdge) from
// evicting the hot xbf gather footprint out of L2/L3.
__device__ __forceinline__ float4 nt_ld_f4(const float* p) {
    floatx4 v = __builtin_nontemporal_load((const floatx4*)p);
    float4 r; r.x = v[0]; r.y = v[1]; r.z = v[2]; r.w = v[3];
    return r;
}
__device__ __forceinline__ int4 nt_ld_i4(const int4* p) {
    intx4 v = __builtin_nontemporal_load((const intx4*)p);
    return make_int4(v[0], v[1], v[2], v[3]);
}

__device__ __forceinline__ int adj_at(const void* adj, int is64, long long pos) {
    if (is64) return (int)((const long long*)adj)[pos];
    return ((const int*)adj)[pos];
}

// Per-wave inline int64-vs-int32 detection: odd dwords of the first 256
// qword-slots are all zero iff adj is int64 (indices < 2^31).
__device__ __forceinline__ int detect64(const int* __restrict__ adj32) {
    int l = threadIdx.x & 63;
    int v = adj32[2 * l + 1] | adj32[2 * (l + 64) + 1]
          | adj32[2 * (l + 128) + 1] | adj32[2 * (l + 192) + 1];
    return (__ballot(v != 0) == 0ull) ? 1 : 0;
}

// ---------------- Fused prep: weights + x->bf16 + hist (one launch) ----------------
__global__ __launch_bounds__(256) void prep_all(
    const float* __restrict__ Wm1, const float* __restrict__ Wm2,
    const float* __restrict__ Wu1, const float* __restrict__ Wu2,
    unsigned short* __restrict__ Wm1t, unsigned short* __restrict__ Wm2t,
    unsigned short* __restrict__ Wu1t, unsigned short* __restrict__ Wu2t,
    const float* __restrict__ x, unsigned short* __restrict__ xbf,
    const void* __restrict__ adj, int* __restrict__ hist)
{
    int bid = blockIdx.x;
    if (bid < PREP_NB) {
        int i = bid * 256 + threadIdx.x;
        if (i < 128 * K1) {
            int n = i / K1, k = i % K1;
            Wm1t[i] = f2bf_rne(Wm1[k * HDIM + n]);
        } else if ((i -= 128 * K1) < 128 * HDIM) {
            int n = i / HDIM, k = i % HDIM;
            Wm2t[i] = f2bf_rne(Wm2[k * HDIM + n]);
        } else if ((i -= 128 * HDIM) < 128 * 256) {
            int n = i / 256, k = i % 256;
            Wu1t[i] = f2bf_rne(Wu1[k * HDIM + n]);
        } else if ((i -= 128 * 256) < 128 * HDIM) {
            int n = i / HDIM, k = i % HDIM;
            Wu2t[i] = f2bf_rne(Wu2[k * HDIM + n]);
        }
    } else if (bid < PREP_NB + X2BF_NB) {
        int i = (bid - PREP_NB) * 256 + threadIdx.x;
        if (i < NNODES * HDIM / 8) {
            const float4* p = (const float4*)(x + i * 8);
            float4 f0 = p[0], f1 = p[1];
            unsigned short s0 = f2bf_rne(f0.x), s1 = f2bf_rne(f0.y), s2 = f2bf_rne(f0.z), s3 = f2bf_rne(f0.w);
            unsigned short s4 = f2bf_rne(f1.x), s5 = f2bf_rne(f1.y), s6 = f2bf_rne(f1.z), s7 = f2bf_rne(f1.w);
            uint4 u;
            u.x = (unsigned)s0 | ((unsigned)s1 << 16);
            u.y = (unsigned)s2 | ((unsigned)s3 << 16);
            u.z = (unsigned)s4 | ((unsigned)s5 << 16);
            u.w = (unsigned)s6 | ((unsigned)s7 << 16);
            *(uint4*)(xbf + i * 8) = u;
        }
    } else {
        int is64 = detect64((const int*)adj);
        int e = (bid - PREP_NB - X2BF_NB) * 256 + threadIdx.x;
        if (e < NEDGES) {
            int r = adj_at(adj, is64, (long long)NEDGES + e);
            atomicAdd(&hist[r], 1);
        }
    }
}

// ---------------- Parallel exclusive scan: block sums, then fused scan ----------------
__global__ __launch_bounds__(256) void scanA_kernel(const int* __restrict__ hist,
                                                    int* __restrict__ bsum)
{
    __shared__ int red[256];
    int i = blockIdx.x * 256 + threadIdx.x;
    int v = (i < NNODES) ? hist[i] : 0;
    red[threadIdx.x] = v;
    __syncthreads();
    for (int d = 128; d > 0; d >>= 1) {
        if (threadIdx.x < d) red[threadIdx.x] += red[threadIdx.x + d];
        __syncthreads();
    }
    if (threadIdx.x == 0) bsum[blockIdx.x] = red[0];
}

// Fused scanB+scanC: each block re-scans the 196 block sums internally.
__global__ __launch_bounds__(256) void scanC_kernel(const int* __restrict__ hist,
                                                    const int* __restrict__ bsum,
                                                    int* __restrict__ cursor)
{
    __shared__ int sb[256];
    __shared__ int s[256];
    int t = threadIdx.x;
    sb[t] = (t < NB) ? bsum[t] : 0;
    int i = blockIdx.x * 256 + t;
    int v = (i < NNODES) ? hist[i] : 0;
    s[t] = v;
    __syncthreads();
    for (int d = 1; d < 256; d <<= 1) {
        int ub = (t >= d) ? sb[t - d] : 0;
        int us = (t >= d) ? s[t - d] : 0;
        __syncthreads();
        sb[t] += ub;
        s[t]  += us;
        __syncthreads();
    }
    int boff = (blockIdx.x == 0) ? 0 : sb[blockIdx.x - 1];
    if (i < NNODES) cursor[i] = boff + s[t] - v;   // exclusive
}

// Packed sorted-edge record: {send, rec, orig_edge, 0} -> one 16B line per edge.
__global__ __launch_bounds__(256) void scatter_kernel(const void* __restrict__ adj,
                                                      int* __restrict__ cursor,
                                                      int4* __restrict__ sEdge)
{
    int is64 = detect64((const int*)adj);
    int e = blockIdx.x * 256 + threadIdx.x;
    if (e < NEDGES) {
        int s = adj_at(adj, is64, e);
        int r = adj_at(adj, is64, (long long)NEDGES + e);
        int pos = atomicAdd(&cursor[r], 1);
        sEdge[pos] = make_int4(s, r, e, 0);
    }
}

// ---------------- Edge kernel: r4 structure (best measured: 341 us) ----------------
// W1 in LDS, W2 persistent in regs, chunk-contiguous tiles, 8-deep bf16 window.
// NEW vs r4: inv and sEdge reads are NON-TEMPORAL -- they are streaming,
// read-once data (102.4 + 12.8 MB) whose cache fills were evicting the hot
// 12.8 MB xbf gather footprint from L3 (r4's 626 MB FETCH ~= compulsory 160 MB
// + ~410 MB of xbf re-fetches = exactly the thrash signature).
__global__ __launch_bounds__(512, 2) void edge_kernel(
    const unsigned short* __restrict__ xbf, const float* __restrict__ inv,
    const int4* __restrict__ sEdge,
    const unsigned short* __restrict__ Wm1t, const float* __restrict__ bm1,
    const unsigned short* __restrict__ Wm2t, const float* __restrict__ bm2,
    const float* __restrict__ We, const float* __restrict__ be,
    float* __restrict__ aggr)
{
    __shared__ unsigned short s_w1[128 * W1STRIDE];      // 75,776 B
    __shared__ unsigned short s_h[8 * 32 * HSTRIDE];     // 67,584 B (wave-private slices)
    __shared__ int s_recb[8 * 32];                       // 1,024 B

    const int t    = threadIdx.x;
    const int l    = t & 63;
    const int wid  = t >> 6;
    const int l15  = l & 15;
    const int quad = l >> 4;

    // Fill W1 LDS (once)
    for (int idx = t; idx < 128 * 36; idx += 512) {
        int n = idx / 36, c = idx % 36;
        *(uint4*)&s_w1[n * W1STRIDE + c * 8] = *(const uint4*)(Wm1t + n * K1 + c * 8);
    }

    // W2 B-fragments resident in registers (r4-proven: fits 128 VGPRs)
    short8 w2f[4][8];
    #pragma unroll
    for (int ks = 0; ks < 4; ++ks)
        #pragma unroll
        for (int nt = 0; nt < 8; ++nt)
            w2f[ks][nt] = *(const short8*)(Wm2t + (nt * 16 + l15) * HDIM + ks * 32 + quad * 8);

    float bm1v[8], bm2v[8], wev[8];
    #pragma unroll
    for (int nt = 0; nt < 8; ++nt) {
        bm1v[nt] = bm1[nt * 16 + l15];
        bm2v[nt] = bm2[nt * 16 + l15];
        wev[nt]  = We[nt * 16 + l15];
    }
    const float be0 = be[0];

    __syncthreads();   // the only barrier

    unsigned short* hbuf = s_h + wid * (32 * HSTRIDE);
    int* srec = s_recb + wid * 32;
    const int gwave  = blockIdx.x * 8 + wid;
    const int nwaves = gridDim.x * 8;
    const int t_lo = (int)((long long)gwave * NTILES_E / nwaves);
    const int t_hi = (int)((long long)(gwave + 1) * NTILES_E / nwaves);
    if (t_lo >= t_hi) return;

    // ---- prologue: first tile's indices + send-side gather steps 0..3 ----
    int4 iA = nt_ld_i4(&sEdge[t_lo * 32 + l15]);
    int4 iB = nt_ld_i4(&sEdge[t_lo * 32 + 16 + l15]);
    unsigned oS0 = (unsigned)iA.x * HDIM, oR0 = (unsigned)iA.y * HDIM, oI0 = (unsigned)iA.z * NINV;
    unsigned oS1 = (unsigned)iB.x * HDIM, oR1 = (unsigned)iB.y * HDIM, oI1 = (unsigned)iB.z * NINV;

    short8 F[8][2];
    #pragma unroll
    for (int s = 0; s < 4; ++s) {
        F[s][0] = *(const short8*)(xbf + oS0 + s * 32 + quad * 8);
        F[s][1] = *(const short8*)(xbf + oS1 + s * 32 + quad * 8);
    }

    for (int tile = t_lo; tile < t_hi; ++tile) {
        const bool nv = (tile + 1) < t_hi;
        int4 nA, nB;
        if (nv) {                              // next tile's indices (sequential, nt-stream)
            nA = nt_ld_i4(&sEdge[(tile + 1) * 32 + l15]);
            nB = nt_ld_i4(&sEdge[(tile + 1) * 32 + 16 + l15]);
        }
        const int re0 = iA.y, re1 = iB.y;      // current tile's rec rows

        // rec-side gathers into F[4..7] + inv raw loads (non-temporal)
        #pragma unroll
        for (int s = 0; s < 4; ++s) {
            F[4 + s][0] = *(const short8*)(xbf + oR0 + s * 32 + quad * 8);
            F[4 + s][1] = *(const short8*)(xbf + oR1 + s * 32 + quad * 8);
        }
        float4 I0[2], I1[2];
        {
            const float* p0 = inv + oI0 + quad * 8;
            const float* p1 = inv + oI1 + quad * 8;
            I0[0] = nt_ld_f4(p0); I0[1] = nt_ld_f4(p0 + 4);
            I1[0] = nt_ld_f4(p1); I1[1] = nt_ld_f4(p1 + 4);
        }

        floatx4 acc[2][8];
        #pragma unroll
        for (int nt = 0; nt < 8; ++nt) {
            acc[0][nt] = (floatx4){bm1v[nt], bm1v[nt], bm1v[nt], bm1v[nt]};
            acc[1][nt] = acc[0][nt];
        }

        // ---- Layer 1: 9 K-steps; B from resident LDS ----
        short8 Fi0, Fi1;
        #pragma unroll
        for (int s = 0; s < 9; ++s) {
            short8 a0, a1;
            if (s < 8) { a0 = F[s][0]; a1 = F[s][1]; }
            else       { a0 = Fi0;     a1 = Fi1;     }
            if (s == 6) {              // convert inv late; loads long since landed
                Fi0 = cvt8(I0[0], I0[1]);
                Fi1 = cvt8(I1[0], I1[1]);
            }
            const unsigned short* wbase = s_w1 + l15 * W1STRIDE + s * 32 + quad * 8;
            #pragma unroll
            for (int nt = 0; nt < 8; ++nt) {
                short8 b = *(const short8*)(wbase + nt * 16 * W1STRIDE);
                acc[0][nt] = __builtin_amdgcn_mfma_f32_16x16x32_bf16(a0, b, acc[0][nt], 0, 0, 0);
                acc[1][nt] = __builtin_amdgcn_mfma_f32_16x16x32_bf16(a1, b, acc[1][nt], 0, 0, 0);
            }
        }

        // ---- L1 epilogue: SiLU -> bf16 h into wave-private LDS (no barrier) ----
        #pragma unroll
        for (int m = 0; m < 2; ++m)
            #pragma unroll
            for (int nt = 0; nt < 8; ++nt)
                #pragma unroll
                for (int r = 0; r < 4; ++r) {
                    float hv = silu_f(acc[m][nt][r]);
                    hbuf[(m * 16 + quad * 4 + r) * HSTRIDE + nt * 16 + l15] =
                        (unsigned short)(__float_as_uint(hv) >> 16);
                }

        #pragma unroll
        for (int nt = 0; nt < 8; ++nt) {
            acc[0][nt] = (floatx4){bm2v[nt], bm2v[nt], bm2v[nt], bm2v[nt]};
            acc[1][nt] = acc[0][nt];
        }

        // ---- Layer 2: 4 K-steps, B from resident regs, A from wave-private LDS ----
        #pragma unroll
        for (int ks = 0; ks < 4; ++ks) {
            short8 a2[2];
            #pragma unroll
            for (int m = 0; m < 2; ++m) {
                int base = (m * 16 + l15) * HSTRIDE + ks * 32 + quad * 8;
                V4S8 v;
                v.d[0] = *(const int2*)(hbuf + base);
                v.d[1] = *(const int2*)(hbuf + base + 4);
                a2[m] = v.s;
            }
            #pragma unroll
            for (int nt = 0; nt < 8; ++nt) {
                acc[0][nt] = __builtin_amdgcn_mfma_f32_16x16x32_bf16(a2[0], w2f[ks][nt], acc[0][nt], 0, 0, 0);
                acc[1][nt] = __builtin_amdgcn_mfma_f32_16x16x32_bf16(a2[1], w2f[ks][nt], acc[1][nt], 0, 0, 0);
            }
        }

        // ---- cross-tile warm start: next tile's send gathers issued before
        //      the long VALU epilogue ----
        if (nv) {
            iA = nA; iB = nB;
            oS0 = (unsigned)iA.x * HDIM; oR0 = (unsigned)iA.y * HDIM; oI0 = (unsigned)iA.z * NINV;
            oS1 = (unsigned)iB.x * HDIM; oR1 = (unsigned)iB.y * HDIM; oI1 = (unsigned)iB.z * NINV;
            #pragma unroll
            for (int s = 0; s < 4; ++s) {
                F[s][0] = *(const short8*)(xbf + oS0 + s * 32 + quad * 8);
                F[s][1] = *(const short8*)(xbf + oS1 + s * 32 + quad * 8);
            }
        }

        // ---- Epilogue: SiLU, gate, segmented reduce over sorted rows ----
        #pragma unroll
        for (int m = 0; m < 2; ++m)
            #pragma unroll
            for (int nt = 0; nt < 8; ++nt)
                #pragma unroll
                for (int r = 0; r < 4; ++r)
                    acc[m][nt][r] = silu_f(acc[m][nt][r]);

        float g[2][4];
        #pragma unroll
        for (int m = 0; m < 2; ++m)
            #pragma unroll
            for (int r = 0; r < 4; ++r) {
                float part = 0.f;
                #pragma unroll
                for (int nt = 0; nt < 8; ++nt)
                    part = fmaf(acc[m][nt][r], wev[nt], part);
                part += __shfl_xor(part, 1);
                part += __shfl_xor(part, 2);
                part += __shfl_xor(part, 4);
                part += __shfl_xor(part, 8);
                g[m][r] = 1.0f / (1.0f + __expf(-(part + be0)));
            }

        // publish this tile's 32 rec values (wave-private, no barrier)
        if (quad == 0) { srec[l15] = re0; srec[16 + l15] = re1; }

        // two 64-column passes through the (now dead) h-buffer as f32
        float* fred = (float*)hbuf;
        #pragma unroll
        for (int half = 0; half < 2; ++half) {
            #pragma unroll
            for (int m = 0; m < 2; ++m)
                #pragma unroll
                for (int nt2 = 0; nt2 < 4; ++nt2)
                    #pragma unroll
                    for (int r = 0; r < 4; ++r)
                        fred[(m * 16 + quad * 4 + r) * FSTRIDE + nt2 * 16 + l15] =
                            acc[m][half * 4 + nt2][r] * g[m][r];

            // lane l owns column half*64 + l; rows sorted by rec ->
            // boundary test is wave-uniform (srec[row] broadcast)
            float* dstbase = aggr + half * 64 + l;
            float sum = 0.f;
            int prev = srec[0];
            #pragma unroll
            for (int row = 0; row < 32; ++row) {
                float v = fred[row * FSTRIDE + l];
                int rc = srec[row];
                if (rc != prev) {
                    atomicAdd(dstbase + (unsigned)prev * HDIM, sum);
                    sum = 0.f;
                    prev = rc;
                }
                sum += v;
            }
            atomicAdd(dstbase + (unsigned)prev * HDIM, sum);
        }
    }
}

// ---------------- Node kernel: persistent grid-stride (r4 structure) ----------------
__global__ __launch_bounds__(256) void node_kernel(
    const float* __restrict__ x, const unsigned short* __restrict__ xbf,
    const float* __restrict__ aggr,
    const unsigned short* __restrict__ Wu1t, const float* __restrict__ bu1,
    const unsigned short* __restrict__ Wu2t, const float* __restrict__ bu2,
    float* __restrict__ out)
{
    __shared__ unsigned short s_u1[128 * U1STRIDE];      // 67,584 B
    __shared__ unsigned short s_h[4 * 32 * HSTRIDE];     // 33,792 B

    const int t    = threadIdx.x;
    const int l    = t & 63;
    const int wid  = t >> 6;
    const int l15  = l & 15;
    const int quad = l >> 4;

    for (int idx = t; idx < 128 * 32; idx += 256) {
        int n = idx / 32, c = idx % 32;
        *(uint4*)&s_u1[n * U1STRIDE + c * 8] = *(const uint4*)(Wu1t + n * 256 + c * 8);
    }

    short8 w2f[4][8];
    #pragma unroll
    for (int ks = 0; ks < 4; ++ks)
        #pragma unroll
        for (int nt = 0; nt < 8; ++nt)
            w2f[ks][nt] = *(const short8*)(Wu2t + (nt * 16 + l15) * HDIM + ks * 32 + quad * 8);

    float bu1v[8], bu2v[8];
    #pragma unroll
    for (int nt = 0; nt < 8; ++nt) {
        bu1v[nt] = bu1[nt * 16 + l15];
        bu2v[nt] = bu2[nt * 16 + l15];
    }

    __syncthreads();

    unsigned short* hbuf = s_h + wid * (32 * HSTRIDE);
    const int nwaves = gridDim.x * 4;

    for (int tile = blockIdx.x * 4 + wid; tile < NTILES_N; tile += nwaves) {
        const int n0 = tile * 32;

        unsigned offX[2];
        #pragma unroll
        for (int m = 0; m < 2; ++m) {
            int row = n0 + m * 16 + l15;
            if (row >= NNODES) row = NNODES - 1;
            offX[m] = (unsigned)row * HDIM;
        }

        floatx4 acc[2][8];
        #pragma unroll
        for (int nt = 0; nt < 8; ++nt) {
            acc[0][nt] = (floatx4){bu1v[nt], bu1v[nt], bu1v[nt], bu1v[nt]};
            acc[1][nt] = acc[0][nt];
        }

        // Layer 1: K=256 ([x | aggr]), 8 K-steps; x side from xbf
        #pragma unroll
        for (int s = 0; s < 8; ++s) {
            short8 a[2];
            #pragma unroll
            for (int m = 0; m < 2; ++m) {
                if (s < 4) {
                    a[m] = *(const short8*)(xbf + offX[m] + s * 32 + quad * 8);
                } else {
                    const float* p = aggr + offX[m] + (s - 4) * 32 + quad * 8;
                    a[m] = cvt8(((const float4*)p)[0], ((const float4*)p)[1]);
                }
            }
            const unsigned short* wbase = s_u1 + l15 * U1STRIDE + s * 32 + quad * 8;
            #pragma unroll
            for (int nt = 0; nt < 8; ++nt) {
                short8 b = *(const short8*)(wbase + nt * 16 * U1STRIDE);
                acc[0][nt] = __builtin_amdgcn_mfma_f32_16x16x32_bf16(a[0], b, acc[0][nt], 0, 0, 0);
                acc[1][nt] = __builtin_amdgcn_mfma_f32_16x16x32_bf16(a[1], b, acc[1][nt], 0, 0, 0);
            }
        }

        #pragma unroll
        for (int m = 0; m < 2; ++m)
            #pragma unroll
            for (int nt = 0; nt < 8; ++nt)
                #pragma unroll
                for (int r = 0; r < 4; ++r) {
                    float hv = silu_f(acc[m][nt][r]);
                    hbuf[(m * 16 + quad * 4 + r) * HSTRIDE + nt * 16 + l15] =
                        (unsigned short)(__float_as_uint(hv) >> 16);
                }

        #pragma unroll
        for (int nt = 0; nt < 8; ++nt) {
            acc[0][nt] = (floatx4){bu2v[nt], bu2v[nt], bu2v[nt], bu2v[nt]};
            acc[1][nt] = acc[0][nt];
        }

        #pragma unroll
        for (int ks = 0; ks < 4; ++ks) {
            short8 a2[2];
            #pragma unroll
            for (int m = 0; m < 2; ++m) {
                int base = (m * 16 + l15) * HSTRIDE + ks * 32 + quad * 8;
                V4S8 v;
                v.d[0] = *(const int2*)(hbuf + base);
                v.d[1] = *(const int2*)(hbuf + base + 4);
                a2[m] = v.s;
            }
            #pragma unroll
            for (int nt = 0; nt < 8; ++nt) {
                acc[0][nt] = __builtin_amdgcn_mfma_f32_16x16x32_bf16(a2[0], w2f[ks][nt], acc[0][nt], 0, 0, 0);
                acc[1][nt] = __builtin_amdgcn_mfma_f32_16x16x32_bf16(a2[1], w2f[ks][nt], acc[1][nt], 0, 0, 0);
            }
        }

        // Residual + store (no activation after layer 2)
        #pragma unroll
        for (int m = 0; m < 2; ++m)
            #pragma unroll
            for (int r = 0; r < 4; ++r) {
                int row = n0 + m * 16 + quad * 4 + r;
                if (row < NNODES) {
                    #pragma unroll
                    for (int nt = 0; nt < 8; ++nt) {
                        int col = nt * 16 + l15;
                        out[(long long)row * HDIM + col] = x[(long long)row * HDIM + col] + acc[m][nt][r];
                    }
                }
            }
    }
}

extern "C" void kernel_launch(void* const* d_in, const int* in_sizes, int n_in,
                              void* d_out, int out_size, void* d_ws, size_t ws_size,
                              hipStream_t stream)
{
    const float* x   = (const float*)d_in[0];
    const void*  adj = d_in[1];
    const float* inv = (const float*)d_in[2];
    const float* Wm1 = (const float*)d_in[3];
    const float* bm1 = (const float*)d_in[4];
    const float* Wm2 = (const float*)d_in[5];
    const float* bm2 = (const float*)d_in[6];
    const float* We  = (const float*)d_in[7];
    const float* be  = (const float*)d_in[8];
    const float* Wu1 = (const float*)d_in[9];
    const float* bu1 = (const float*)d_in[10];
    const float* Wu2 = (const float*)d_in[11];
    const float* bu2 = (const float*)d_in[12];
    float* out = (float*)d_out;

    char* ws = (char*)d_ws;
    float* aggr = (float*)ws;
    size_t off = (size_t)NNODES * HDIM * 4;                              // 25,600,000
    int* hist   = (int*)(ws + off);          off += (size_t)NNODES * 4;  // contiguous with aggr -> one memset
    unsigned short* Wm1t = (unsigned short*)(ws + off);  off += 128 * K1 * 2;
    unsigned short* Wm2t = (unsigned short*)(ws + off);  off += 128 * HDIM * 2;
    unsigned short* Wu1t = (unsigned short*)(ws + off);  off += 128 * 256 * 2;
    unsigned short* Wu2t = (unsigned short*)(ws + off);  off += 128 * HDIM * 2;
    off = (off + 63) & ~(size_t)63;
    unsigned short* xbf = (unsigned short*)(ws + off);   off += (size_t)NNODES * HDIM * 2;
    int* cursor = (int*)(ws + off);          off += (size_t)NNODES * 4;
    int* bsum   = (int*)(ws + off);          off += 1024;
    off = (off + 63) & ~(size_t)63;
    int4* sEdge = (int4*)(ws + off);         off += (size_t)NEDGES * 16;

    hipMemsetAsync(aggr, 0, (size_t)(NNODES * HDIM + NNODES) * sizeof(float), stream);
    prep_all<<<PREP_NB + X2BF_NB + HIST_NB, 256, 0, stream>>>(
        Wm1, Wm2, Wu1, Wu2, Wm1t, Wm2t, Wu1t, Wu2t, x, xbf, adj, hist);
    scanA_kernel<<<NB, 256, 0, stream>>>(hist, bsum);
    scanC_kernel<<<NB, 256, 0, stream>>>(hist, bsum, cursor);
    scatter_kernel<<<(NEDGES + 255) / 256, 256, 0, stream>>>(adj, cursor, sEdge);
    edge_kernel<<<256, 512, 0, stream>>>(xbf, inv, sEdge,
                                         Wm1t, bm1, Wm2t, bm2, We, be, aggr);
    node_kernel<<<256, 256, 0, stream>>>(x, xbf, aggr, Wu1t, bu1, Wu2t, bu2, out);
}